// Round 10
// baseline (222.821 us; speedup 1.0000x reference)
//
#include <hip/hip_runtime.h>
#include <hip/hip_bf16.h>
#include <math.h>

#define BB 2
#define TT 2048
#define CC 1024
#define HH 16
#define DD 64
#define C3 3072
#define BT 4096

typedef __attribute__((ext_vector_type(8))) short short8;
typedef __attribute__((ext_vector_type(8))) unsigned short ushort8;
typedef __attribute__((ext_vector_type(4))) unsigned short ushort4v;
typedef __attribute__((ext_vector_type(4))) float floatx4;
typedef __attribute__((ext_vector_type(16))) float floatx16;

// fp32 -> bf16, round-to-nearest-even
__device__ __forceinline__ unsigned short f2b(float f) {
    union { float f; unsigned int u; } v; v.f = f;
    unsigned int u = v.u;
    unsigned int r = (u + 0x7fffu + ((u >> 16) & 1u)) >> 16;
    return (unsigned short)r;
}
// cheap round-half-up (for P weights; positive values)
__device__ __forceinline__ unsigned short f2b_fast(float f) {
    unsigned int u = __builtin_bit_cast(unsigned int, f);
    return (unsigned short)((u + 0x8000u) >> 16);
}

__device__ __forceinline__ void store_out(unsigned short* p, float v) { *p = f2b(v); }
__device__ __forceinline__ void store_out(float* p, float v) { *p = v; }

// async 16B global -> LDS (lane-linear dest: wave-uniform base + lane*16)
__device__ __forceinline__ void async16(const unsigned short* g, unsigned short* lds) {
    __builtin_amdgcn_global_load_lds(
        (const __attribute__((address_space(1))) unsigned int*)g,
        (__attribute__((address_space(3))) unsigned int*)lds, 16, 0, 0);
}

// ---------------------------------------------------------------------------
// Prep kernel: blocks 0..2047 cast x fp32->bf16 (8 elems/thread);
// blocks 2048..3071 transpose+cast the two weight matrices (64x64 tiles).
// ---------------------------------------------------------------------------
__global__ __launch_bounds__(256) void prep_kernel(
    const float* __restrict__ x, unsigned short* __restrict__ xb,
    const float* __restrict__ Wqkv, const float* __restrict__ Wproj,
    unsigned short* __restrict__ Wqkv_t, unsigned short* __restrict__ Wproj_t)
{
    __shared__ float tile[64 * 65];
    const int tid = threadIdx.x;
    const int bid = blockIdx.x;

    if (bid < 2048) {                      // ---- cast x ----
        int i = bid * 256 + tid;
        const float4 v0 = *(const float4*)&x[(size_t)i * 8];
        const float4 v1 = *(const float4*)&x[(size_t)i * 8 + 4];
        ushort8 pk;
        pk[0] = f2b(v0.x); pk[1] = f2b(v0.y); pk[2] = f2b(v0.z); pk[3] = f2b(v0.w);
        pk[4] = f2b(v1.x); pk[5] = f2b(v1.y); pk[6] = f2b(v1.z); pk[7] = f2b(v1.w);
        *(ushort8*)&xb[(size_t)i * 8] = pk;
        return;
    }

    // ---- weight transposes ----
    const int xt = bid - 2048;             // 0..1023
    const int cxt = xt & 63;               // col-tile
    const int r0  = (xt >> 6) * 64;        // row-tile base
    const float* src; unsigned short* dst; int Ccols, c0;
    if (cxt < 48) { src = Wqkv;  dst = Wqkv_t;  Ccols = C3; c0 = cxt * 64; }
    else          { src = Wproj; dst = Wproj_t; Ccols = CC; c0 = (cxt - 48) * 64; }
#pragma unroll
    for (int it = 0; it < 4; it++) {
        int idx = it * 256 + tid;
        int row = idx >> 4;
        int c4  = idx & 15;
        float4 v = *(const float4*)&src[(size_t)(r0 + row) * Ccols + c0 + c4 * 4];
        tile[row * 65 + c4 * 4 + 0] = v.x;
        tile[row * 65 + c4 * 4 + 1] = v.y;
        tile[row * 65 + c4 * 4 + 2] = v.z;
        tile[row * 65 + c4 * 4 + 3] = v.w;
    }
    __syncthreads();
#pragma unroll
    for (int it = 0; it < 2; it++) {
        int idx = it * 256 + tid;
        int orow = idx >> 3;
        int o8   = idx & 7;
        ushort8 pk;
#pragma unroll
        for (int j = 0; j < 8; j++) pk[j] = f2b(tile[(o8 * 8 + j) * 65 + orow]);
        *(ushort8*)&dst[(size_t)(c0 + orow) * CC + r0 + o8 * 8] = pk;
    }
}

// ---------------------------------------------------------------------------
// bf16 GEMM, B transposed (unchanged from R9): 128x128, BK=64, XOR swizzle.
// If WVT: blocks covering cols [2C,3C) also store V transposed into Vt.
// ---------------------------------------------------------------------------
template <typename OUT_T, bool WVT>
__global__ __launch_bounds__(256) void gemm_bt_kernel(
    const unsigned short* __restrict__ A, const unsigned short* __restrict__ Bm,
    const float* __restrict__ bias, OUT_T* __restrict__ Cmat,
    unsigned short* __restrict__ Vt,
    int M, int N, int K, float qscale, int qcols)
{
    __shared__ __align__(16) unsigned short sA[128 * 64];
    __shared__ __align__(16) unsigned short sB[128 * 64];

    const int tid = threadIdx.x;
    const int lane16 = tid & 15, quad = (tid & 63) >> 4;
    const int w = tid >> 6;
    const int wm = w >> 1, wn = w & 1;
    const int m0 = blockIdx.y * 128, n0 = blockIdx.x * 128;
    const int lx = lane16 & 7;

    floatx4 acc[4][4] = {};

    for (int kt = 0; kt < K; kt += 64) {
#pragma unroll
        for (int it = 0; it < 4; it++) {
            int idx = it * 256 + tid;
            int row = idx >> 3;
            int c8m = (idx & 7) ^ (row & 7);
            int wslot = it * 256 + (tid & 192);
            async16(&A[(size_t)(m0 + row) * K + kt + c8m * 8], &sA[wslot * 8]);
            async16(&Bm[(size_t)(n0 + row) * K + kt + c8m * 8], &sB[wslot * 8]);
        }
        __syncthreads();
#pragma unroll
        for (int ks = 0; ks < 64; ks += 32) {
            const int slot = ((ks >> 3) + quad) ^ lx;
            short8 af[4], bf[4];
#pragma unroll
            for (int t = 0; t < 4; t++) {
                af[t] = *(const short8*)&sA[(wm * 64 + t * 16 + lane16) * 64 + slot * 8];
                bf[t] = *(const short8*)&sB[(wn * 64 + t * 16 + lane16) * 64 + slot * 8];
            }
#pragma unroll
            for (int mt = 0; mt < 4; mt++)
#pragma unroll
                for (int nt = 0; nt < 4; nt++)
                    acc[mt][nt] = __builtin_amdgcn_mfma_f32_16x16x32_bf16(
                        af[mt], bf[nt], acc[mt][nt], 0, 0, 0);
        }
        __syncthreads();
    }

#pragma unroll
    for (int mt = 0; mt < 4; mt++) {
#pragma unroll
        for (int nt = 0; nt < 4; nt++) {
            int col = n0 + wn * 64 + nt * 16 + lane16;
            float bv = bias[col];
            float sc = (col < qcols) ? qscale : 1.0f;
            float v[4];
            int row0 = m0 + wm * 64 + mt * 16 + quad * 4;
#pragma unroll
            for (int r = 0; r < 4; r++) {
                v[r] = (acc[mt][nt][r] + bv) * sc;
                store_out(&Cmat[(size_t)(row0 + r) * N + col], v[r]);
            }
            if (WVT && n0 >= 2 * CC) {
                int hd = col - 2 * CC;
                int b  = row0 >> 11;
                int token = row0 & (TT - 1);
                ushort4v pk;
#pragma unroll
                for (int r = 0; r < 4; r++) pk[r] = f2b(v[r]);
                *(ushort4v*)&Vt[((size_t)(b * HH * DD) + hd) * TT + token] = pk;
            }
        }
    }
}

// ---------------------------------------------------------------------------
// Flash attention, 32x32x16 bf16 MFMA, split-K wave pairs.
// Grid (16 g, 32 bh), 256 threads = 4 waves. Wave w: wq=w&1 owns 32 queries
// (half of the 64q tile), wk=w>>1 owns the parity of 64-key subtiles.
// 128 keys staged per iteration; partial O/psum combined via LDS per pass
// (no-max softmax is linear in partials). Pairing (31-g, g) -> ~17 iters.
// Q pre-scaled by log2(e)/8 in GEMM1 epilogue -> exp2f softmax.
// 32x32x16 layouts: A m=lane&31,k=(lane>>5)*8+j; B n=lane&31 same k;
// C/D col=lane&31,row=(reg&3)+8*(reg>>2)+4*(lane>>5).
// ---------------------------------------------------------------------------
__global__ __launch_bounds__(256) void attn_mfma_kernel(
    const unsigned short* __restrict__ qkv, const unsigned short* __restrict__ Vt,
    unsigned short* __restrict__ att)
{
    __shared__ __align__(16) unsigned short Ks[128 * 72];   // [key 0..127][d], pad->72
    __shared__ __align__(16) unsigned short Vs[64 * 136];   // [d 0..63][key 0..127], pad->136
    __shared__ __align__(16) unsigned short Pl[64 * 132];   // [q-local][key], pad->132

    const int tid = threadIdx.x;
    const int lane = tid & 63;
    const int ln31 = lane & 31, half = lane >> 5;
    const int w = tid >> 6;
    const int wq = w & 1, wk = w >> 1;
    const int g  = blockIdx.x;                    // 0..15
    const int bh = blockIdx.y;
    const int b = bh >> 4, h = bh & 15;

    // staging coords (constant per thread)
    const int kcol = (tid & 7) * 8,  krow0 = tid >> 3;   // Ks: rows krow0+32*it
    const int vcol = (tid & 15) * 8, vrow0 = tid >> 4;   // Vs: rows vrow0+16*it

    const unsigned short* kgbase = &qkv[(size_t)(b * TT) * C3 + CC + h * DD + kcol];
    const unsigned short* vgbase = &Vt[(size_t)(bh * DD) * TT + vcol];

    float* Oswf = (float*)Ks;        // 64q x 64d fp32 = 16 KB (fits in Ks)
    float* psw  = (float*)Vs;        // 64 floats

    for (int pass = 0; pass < 2; ++pass) {
        const int p  = pass ? g : (31 - g);       // 64q tile index, heavy first
        const int qb = p * 64 + wq * 32;          // wave's 32 queries

        // Q fragments: qf[s] covers k = s*16 + half*8 + j
        short8 qf[4];
        {
            const unsigned short* qp =
                &qkv[(size_t)(b * TT + qb + ln31) * C3 + h * DD + half * 8];
#pragma unroll
            for (int s = 0; s < 4; s++) qf[s] = *(const short8*)&qp[s * 16];
        }

        float psum[16] = {};
        floatx16 O[2] = {};

        const int J = (p >> 1) + 1;               // 128-key iterations

        // prefetch iter 0
        ushort8 kpre[4], vpre[4];
#pragma unroll
        for (int it = 0; it < 4; it++) {
            kpre[it] = *(const ushort8*)&kgbase[(size_t)(krow0 + 32 * it) * C3];
            vpre[it] = *(const ushort8*)&vgbase[(size_t)(vrow0 + 16 * it) * TT];
        }

        for (int j = 0; j < J; ++j) {
            const int kb = j * 128;
            __syncthreads();                      // prior readers (or prior-pass epilogue) done
#pragma unroll
            for (int it = 0; it < 4; it++) {
                *(ushort8*)&Ks[(krow0 + 32 * it) * 72 + kcol] = kpre[it];
                *(ushort8*)&Vs[(vrow0 + 16 * it) * 136 + vcol] = vpre[it];
            }
            __syncthreads();

            if (j + 1 < J) {                      // overlap next iteration's loads
                const int kn = kb + 128;
#pragma unroll
                for (int it = 0; it < 4; it++) {
                    kpre[it] = *(const ushort8*)&kgbase[(size_t)(kn + krow0 + 32 * it) * C3];
                    vpre[it] = *(const ushort8*)&vgbase[(size_t)(vrow0 + 16 * it) * TT + kn];
                }
            }

            const int tk = 2 * j + wk;            // this wave's 64-key subtile
            if (tk <= p) {                        // wave-uniform
                const int klocal = wk * 64;       // offset within staged 128 keys

                // ---- S = Q K^T : 2 key-blocks x 4 k-steps ----
                floatx16 s4[2] = {};
#pragma unroll
                for (int nt = 0; nt < 2; nt++) {
                    const int krow = klocal + nt * 32 + ln31;
#pragma unroll
                    for (int s = 0; s < 4; s++) {
                        short8 kf = *(const short8*)&Ks[krow * 72 + s * 16 + half * 8];
                        s4[nt] = __builtin_amdgcn_mfma_f32_32x32x16_bf16(qf[s], kf, s4[nt], 0, 0, 0);
                    }
                }

                // ---- softmax: p = exp2(s), accumulate psum, stage P ----
                const bool diag = (tk == p);
#pragma unroll
                for (int nt = 0; nt < 2; nt++) {
                    const int key = kb + klocal + nt * 32 + ln31;
#pragma unroll
                    for (int reg = 0; reg < 16; reg++) {
                        const int qrow = (reg & 3) + 8 * (reg >> 2) + 4 * half;
                        float v = s4[nt][reg];
                        if (diag) v = (key > qb + qrow) ? -1e30f : v;
                        float pe = exp2f(v);
                        psum[reg] += pe;
                        Pl[(wq * 32 + qrow) * 132 + klocal + nt * 32 + ln31] = f2b_fast(pe);
                    }
                }
                __threadfence_block();

                // ---- O += P V : 2 d-blocks x 4 k-steps ----
                short8 pf[4];
#pragma unroll
                for (int ks = 0; ks < 4; ks++)
                    pf[ks] = *(const short8*)&Pl[(wq * 32 + ln31) * 132 + klocal + ks * 16 + half * 8];
#pragma unroll
                for (int dt = 0; dt < 2; dt++) {
                    const int vrow = dt * 32 + ln31;
#pragma unroll
                    for (int ks = 0; ks < 4; ks++) {
                        short8 vf = *(const short8*)&Vs[vrow * 136 + klocal + ks * 16 + half * 8];
                        O[dt] = __builtin_amdgcn_mfma_f32_32x32x16_bf16(pf[ks], vf, O[dt], 0, 0, 0);
                    }
                }
            }
        }

        // ---- intra-wave psum reduction (32 lanes of a half hold each row) ----
#pragma unroll
        for (int off = 1; off <= 16; off <<= 1)
#pragma unroll
            for (int reg = 0; reg < 16; reg++)
                psum[reg] += __shfl_xor(psum[reg], off, 64);

        // ---- cross-parity combine via LDS ----
        __syncthreads();                          // all Ks/Vs/Pl reads done
        if (wk == 1) {
#pragma unroll
            for (int reg = 0; reg < 16; reg++) {
                const int qrow = (reg & 3) + 8 * (reg >> 2) + 4 * half;
                Oswf[(wq * 32 + qrow) * 64 + ln31]      = O[0][reg];
                Oswf[(wq * 32 + qrow) * 64 + 32 + ln31] = O[1][reg];
                psw[wq * 32 + qrow] = psum[reg];      // same value from all 32 lanes
            }
        }
        __syncthreads();
        if (wk == 0) {
#pragma unroll
            for (int reg = 0; reg < 16; reg++) {
                const int qrow = (reg & 3) + 8 * (reg >> 2) + 4 * half;
                const float rl = 1.0f / (psum[reg] + psw[wq * 32 + qrow]);
                const size_t obase = (size_t)(b * TT + qb + qrow) * CC + h * DD;
                float v0 = O[0][reg] + Oswf[(wq * 32 + qrow) * 64 + ln31];
                float v1 = O[1][reg] + Oswf[(wq * 32 + qrow) * 64 + 32 + ln31];
                att[obase + ln31]      = f2b(v0 * rl);
                att[obase + 32 + ln31] = f2b(v1 * rl);
            }
        }
        // next pass's first __syncthreads() guards Osw/psw reads vs restaging
    }
}

// ---------------------------------------------------------------------------
extern "C" void kernel_launch(void* const* d_in, const int* in_sizes, int n_in,
                              void* d_out, int out_size, void* d_ws, size_t ws_size,
                              hipStream_t stream) {
    const float* x     = (const float*)d_in[0];
    const float* Wqkv  = (const float*)d_in[1];
    const float* bqkv  = (const float*)d_in[2];
    const float* Wproj = (const float*)d_in[3];
    const float* bproj = (const float*)d_in[4];
    float* out = (float*)d_out;

    unsigned short* xb      = (unsigned short*)d_ws;            // [4096][1024]
    unsigned short* qkv_b   = xb      + (size_t)BT * CC;        // [4096][3072]
    unsigned short* Wqkv_t  = qkv_b   + (size_t)BT * C3;        // [3072][1024]
    unsigned short* Wproj_t = Wqkv_t  + (size_t)C3 * CC;        // [1024][1024]
    unsigned short* Vt      = Wproj_t + (size_t)CC * CC;        // [32][64][2048]
    unsigned short* att_b   = Vt      + (size_t)BB * HH * DD * TT; // [4096][1024]

    // 1) input cast + weight transposes (one launch)
    prep_kernel<<<3072, 256, 0, stream>>>(x, xb, Wqkv, Wproj, Wqkv_t, Wproj_t);

    // 2) QKV GEMM -> bf16 (Q pre-scaled by log2(e)/8; V also written transposed)
    {
        dim3 grid(C3 / 128, BT / 128);
        gemm_bt_kernel<unsigned short, true><<<grid, 256, 0, stream>>>(
            xb, Wqkv_t, bqkv, qkv_b, Vt, BT, C3, CC, 0.125f * 1.44269504f, CC);
    }
    // 3) flash attention (32x32 MFMA, split-K wave pairs, paired q-tiles)
    {
        dim3 grid(16, BB * HH);
        attn_mfma_kernel<<<grid, 256, 0, stream>>>(qkv_b, Vt, att_b);
    }
    // 4) projection GEMM -> fp32 out
    {
        dim3 grid(CC / 128, BT / 128);
        gemm_bt_kernel<float, false><<<grid, 256, 0, stream>>>(
            att_b, Wproj_t, bproj, out, nullptr, BT, CC, CC, 1.0f, 0);
    }
}

// Round 11
// 184.190 us; speedup vs baseline: 1.2097x; 1.2097x over previous
//
#include <hip/hip_runtime.h>
#include <hip/hip_bf16.h>
#include <math.h>

#define BB 2
#define TT 2048
#define CC 1024
#define HH 16
#define DD 64
#define C3 3072
#define BT 4096

typedef __attribute__((ext_vector_type(8))) short short8;
typedef __attribute__((ext_vector_type(8))) unsigned short ushort8;
typedef __attribute__((ext_vector_type(4))) unsigned short ushort4v;
typedef __attribute__((ext_vector_type(4))) float floatx4;

// fp32 -> bf16, round-to-nearest-even
__device__ __forceinline__ unsigned short f2b(float f) {
    union { float f; unsigned int u; } v; v.f = f;
    unsigned int u = v.u;
    unsigned int r = (u + 0x7fffu + ((u >> 16) & 1u)) >> 16;
    return (unsigned short)r;
}
// cheap round-half-up (for P weights; positive values)
__device__ __forceinline__ unsigned short f2b_fast(float f) {
    unsigned int u = __builtin_bit_cast(unsigned int, f);
    return (unsigned short)((u + 0x8000u) >> 16);
}

__device__ __forceinline__ void store_out(unsigned short* p, float v) { *p = f2b(v); }
__device__ __forceinline__ void store_out(float* p, float v) { *p = v; }

// async 16B global -> LDS (lane-linear dest: wave-uniform base + lane*16)
__device__ __forceinline__ void async16(const unsigned short* g, unsigned short* lds) {
    __builtin_amdgcn_global_load_lds(
        (const __attribute__((address_space(1))) unsigned int*)g,
        (__attribute__((address_space(3))) unsigned int*)lds, 16, 0, 0);
}

// ---------------------------------------------------------------------------
// Prep kernel: blocks 0..2047 cast x fp32->bf16 (8 elems/thread);
// blocks 2048..3071 transpose+cast the two weight matrices (64x64 tiles).
// ---------------------------------------------------------------------------
__global__ __launch_bounds__(256) void prep_kernel(
    const float* __restrict__ x, unsigned short* __restrict__ xb,
    const float* __restrict__ Wqkv, const float* __restrict__ Wproj,
    unsigned short* __restrict__ Wqkv_t, unsigned short* __restrict__ Wproj_t)
{
    __shared__ float tile[64 * 65];
    const int tid = threadIdx.x;
    const int bid = blockIdx.x;

    if (bid < 2048) {                      // ---- cast x ----
        int i = bid * 256 + tid;
        const float4 v0 = *(const float4*)&x[(size_t)i * 8];
        const float4 v1 = *(const float4*)&x[(size_t)i * 8 + 4];
        ushort8 pk;
        pk[0] = f2b(v0.x); pk[1] = f2b(v0.y); pk[2] = f2b(v0.z); pk[3] = f2b(v0.w);
        pk[4] = f2b(v1.x); pk[5] = f2b(v1.y); pk[6] = f2b(v1.z); pk[7] = f2b(v1.w);
        *(ushort8*)&xb[(size_t)i * 8] = pk;
        return;
    }

    // ---- weight transposes ----
    const int xt = bid - 2048;             // 0..1023
    const int cxt = xt & 63;               // col-tile
    const int r0  = (xt >> 6) * 64;        // row-tile base
    const float* src; unsigned short* dst; int Ccols, c0;
    if (cxt < 48) { src = Wqkv;  dst = Wqkv_t;  Ccols = C3; c0 = cxt * 64; }
    else          { src = Wproj; dst = Wproj_t; Ccols = CC; c0 = (cxt - 48) * 64; }
#pragma unroll
    for (int it = 0; it < 4; it++) {
        int idx = it * 256 + tid;
        int row = idx >> 4;
        int c4  = idx & 15;
        float4 v = *(const float4*)&src[(size_t)(r0 + row) * Ccols + c0 + c4 * 4];
        tile[row * 65 + c4 * 4 + 0] = v.x;
        tile[row * 65 + c4 * 4 + 1] = v.y;
        tile[row * 65 + c4 * 4 + 2] = v.z;
        tile[row * 65 + c4 * 4 + 3] = v.w;
    }
    __syncthreads();
#pragma unroll
    for (int it = 0; it < 2; it++) {
        int idx = it * 256 + tid;
        int orow = idx >> 3;
        int o8   = idx & 7;
        ushort8 pk;
#pragma unroll
        for (int j = 0; j < 8; j++) pk[j] = f2b(tile[(o8 * 8 + j) * 65 + orow]);
        *(ushort8*)&dst[(size_t)(c0 + orow) * CC + r0 + o8 * 8] = pk;
    }
}

// ---------------------------------------------------------------------------
// bf16 GEMM, B transposed: 128x128, BK=64, XOR chunk swizzle.
// If WVT: blocks covering cols [2C,3C) also store V transposed into Vt.
// ---------------------------------------------------------------------------
template <typename OUT_T, bool WVT>
__global__ __launch_bounds__(256) void gemm_bt_kernel(
    const unsigned short* __restrict__ A, const unsigned short* __restrict__ Bm,
    const float* __restrict__ bias, OUT_T* __restrict__ Cmat,
    unsigned short* __restrict__ Vt,
    int M, int N, int K, float qscale, int qcols)
{
    __shared__ __align__(16) unsigned short sA[128 * 64];
    __shared__ __align__(16) unsigned short sB[128 * 64];

    const int tid = threadIdx.x;
    const int lane16 = tid & 15, quad = (tid & 63) >> 4;
    const int w = tid >> 6;
    const int wm = w >> 1, wn = w & 1;
    const int m0 = blockIdx.y * 128, n0 = blockIdx.x * 128;
    const int lx = lane16 & 7;

    floatx4 acc[4][4] = {};

    for (int kt = 0; kt < K; kt += 64) {
#pragma unroll
        for (int it = 0; it < 4; it++) {
            int idx = it * 256 + tid;
            int row = idx >> 3;
            int c8m = (idx & 7) ^ (row & 7);
            int wslot = it * 256 + (tid & 192);
            async16(&A[(size_t)(m0 + row) * K + kt + c8m * 8], &sA[wslot * 8]);
            async16(&Bm[(size_t)(n0 + row) * K + kt + c8m * 8], &sB[wslot * 8]);
        }
        __syncthreads();
#pragma unroll
        for (int ks = 0; ks < 64; ks += 32) {
            const int slot = ((ks >> 3) + quad) ^ lx;
            short8 af[4], bf[4];
#pragma unroll
            for (int t = 0; t < 4; t++) {
                af[t] = *(const short8*)&sA[(wm * 64 + t * 16 + lane16) * 64 + slot * 8];
                bf[t] = *(const short8*)&sB[(wn * 64 + t * 16 + lane16) * 64 + slot * 8];
            }
#pragma unroll
            for (int mt = 0; mt < 4; mt++)
#pragma unroll
                for (int nt = 0; nt < 4; nt++)
                    acc[mt][nt] = __builtin_amdgcn_mfma_f32_16x16x32_bf16(
                        af[mt], bf[nt], acc[mt][nt], 0, 0, 0);
        }
        __syncthreads();
    }

#pragma unroll
    for (int mt = 0; mt < 4; mt++) {
#pragma unroll
        for (int nt = 0; nt < 4; nt++) {
            int col = n0 + wn * 64 + nt * 16 + lane16;
            float bv = bias[col];
            float sc = (col < qcols) ? qscale : 1.0f;
            float v[4];
            int row0 = m0 + wm * 64 + mt * 16 + quad * 4;
#pragma unroll
            for (int r = 0; r < 4; r++) {
                v[r] = (acc[mt][nt][r] + bv) * sc;
                store_out(&Cmat[(size_t)(row0 + r) * N + col], v[r]);
            }
            if (WVT && n0 >= 2 * CC) {
                int hd = col - 2 * CC;
                int b  = row0 >> 11;
                int token = row0 & (TT - 1);
                ushort4v pk;
#pragma unroll
                for (int r = 0; r < 4; r++) pk[r] = f2b(v[r]);
                *(ushort4v*)&Vt[((size_t)(b * HH * DD) + hd) * TT + token] = pk;
            }
        }
    }
}

// ---------------------------------------------------------------------------
// Flash attention, bf16 16x16x32 MFMA, no-running-max softmax.
// Grid (B*H, 16): x = bh -> linear id % 8 = bh % 8 -> all 16 blocks of a
// head share one XCD's L2 (4 heads/XCD, 2 MB K/V fits 4 MB L2).
// Block (bh, g): q-tile 31-g (heavy) then q-tile g (light) = 33 balanced
// K-tile units. Q pre-scaled by log2(e)/8 in GEMM1 -> raw v_exp_f32 here
// (__builtin_amdgcn_exp2f; libm exp2f's slow path caused the R9 regression).
// ---------------------------------------------------------------------------
__global__ __launch_bounds__(256) void attn_mfma_kernel(
    const unsigned short* __restrict__ qkv, const unsigned short* __restrict__ Vt,
    unsigned short* __restrict__ att)
{
    __shared__ __align__(16) unsigned short Ks[64 * 72];
    __shared__ __align__(16) unsigned short Vs[64 * 72];
    __shared__ __align__(16) unsigned short Pl[64 * 76];   // stride 76: conflict-free scatter

    const int tid = threadIdx.x;
    const int l = tid & 63;
    const int lane16 = l & 15, quad = l >> 4;
    const int w = tid >> 6;
    const int bh = blockIdx.x;                    // same head -> same XCD
    const int b = bh >> 4, h = bh & 15;
    const int g = blockIdx.y;                     // 0..15

    // staging coords: each thread owns rows srow and srow+32, 16B chunk sc8
    const int srow = tid >> 3;
    const int sc8  = (tid & 7) * 8;
    const unsigned short* kbase = &qkv[(size_t)(b * TT) * C3 + CC + h * DD + sc8];
    const unsigned short* vbase = &Vt[(size_t)(bh * DD + srow) * TT + sc8];

#pragma unroll
    for (int pass = 0; pass < 2; ++pass) {
        const int p  = pass ? g : (31 - g);       // heavy tile first
        const int q0 = p * 64;
        const int qw = q0 + w * 16;

        // Q fragments (A layout: m=lane16, k=quad*8+j)
        short8 qf[2];
        {
            const unsigned short* qp =
                &qkv[(size_t)(b * TT + qw + lane16) * C3 + h * DD + quad * 8];
            qf[0] = *(const short8*)&qp[0];
            qf[1] = *(const short8*)&qp[32];
        }

        float psum[4] = {0.f, 0.f, 0.f, 0.f};
        floatx4 O[4] = {};

        // prefetch tile 0 into registers
        ushort8 kr0 = *(const ushort8*)&kbase[(size_t)srow * C3];
        ushort8 kr1 = *(const ushort8*)&kbase[(size_t)(srow + 32) * C3];
        ushort8 vr0 = *(const ushort8*)&vbase[0];
        ushort8 vr1 = *(const ushort8*)&vbase[(size_t)32 * TT];

        const int ntiles = p + 1;
        for (int t = 0; t < ntiles; ++t) {
            const int k0 = t * 64;
            __syncthreads();                       // previous tile's LDS readers done
            *(ushort8*)&Ks[srow * 72 + sc8]        = kr0;
            *(ushort8*)&Ks[(srow + 32) * 72 + sc8] = kr1;
            *(ushort8*)&Vs[srow * 72 + sc8]        = vr0;
            *(ushort8*)&Vs[(srow + 32) * 72 + sc8] = vr1;
            __syncthreads();

            if (t + 1 < ntiles) {                  // overlap next tile's global loads
                const int kn = k0 + 64;
                kr0 = *(const ushort8*)&kbase[(size_t)(kn + srow) * C3];
                kr1 = *(const ushort8*)&kbase[(size_t)(kn + srow + 32) * C3];
                vr0 = *(const ushort8*)&vbase[kn];
                vr1 = *(const ushort8*)&vbase[(size_t)32 * TT + kn];
            }

            // ---- S = Q K^T ----
            floatx4 s4[4] = {};
#pragma unroll
            for (int nt = 0; nt < 4; nt++) {
                short8 kf0 = *(const short8*)&Ks[(nt * 16 + lane16) * 72 + quad * 8];
                short8 kf1 = *(const short8*)&Ks[(nt * 16 + lane16) * 72 + 32 + quad * 8];
                s4[nt] = __builtin_amdgcn_mfma_f32_16x16x32_bf16(qf[0], kf0, s4[nt], 0, 0, 0);
                s4[nt] = __builtin_amdgcn_mfma_f32_16x16x32_bf16(qf[1], kf1, s4[nt], 0, 0, 0);
            }

            // ---- p = exp2(s) (log2e folded into Q), stage P (C -> A layout) ----
            if (t == ntiles - 1) {                 // diag tile: causal mask (wave-uniform)
#pragma unroll
                for (int nt = 0; nt < 4; nt++) {
                    int key = k0 + nt * 16 + lane16;
#pragma unroll
                    for (int r = 0; r < 4; r++) {
                        float v = (key > qw + quad * 4 + r) ? -1e30f : s4[nt][r];
                        float pe = __builtin_amdgcn_exp2f(v);
                        psum[r] += pe;
                        Pl[(w * 16 + quad * 4 + r) * 76 + nt * 16 + lane16] = f2b_fast(pe);
                    }
                }
            } else {                               // interior tile: no mask
#pragma unroll
                for (int nt = 0; nt < 4; nt++) {
#pragma unroll
                    for (int r = 0; r < 4; r++) {
                        float pe = __builtin_amdgcn_exp2f(s4[nt][r]);
                        psum[r] += pe;
                        Pl[(w * 16 + quad * 4 + r) * 76 + nt * 16 + lane16] = f2b_fast(pe);
                    }
                }
            }
            __threadfence_block();   // Pl writes -> Pl reads (same wave region)

            // ---- O += P V ----
            short8 pf0 = *(const short8*)&Pl[(w * 16 + lane16) * 76 + quad * 8];
            short8 pf1 = *(const short8*)&Pl[(w * 16 + lane16) * 76 + 32 + quad * 8];
#pragma unroll
            for (int dt = 0; dt < 4; dt++) {
                short8 vf0 = *(const short8*)&Vs[(dt * 16 + lane16) * 72 + quad * 8];
                short8 vf1 = *(const short8*)&Vs[(dt * 16 + lane16) * 72 + 32 + quad * 8];
                O[dt] = __builtin_amdgcn_mfma_f32_16x16x32_bf16(pf0, vf0, O[dt], 0, 0, 0);
                O[dt] = __builtin_amdgcn_mfma_f32_16x16x32_bf16(pf1, vf1, O[dt], 0, 0, 0);
            }
        }

        // final reduction of l across the 16 lanes holding each row
#pragma unroll
        for (int off = 1; off <= 8; off <<= 1)
#pragma unroll
            for (int r = 0; r < 4; r++)
                psum[r] += __shfl_xor(psum[r], off, 64);

        float rl[4];
#pragma unroll
        for (int r = 0; r < 4; r++) rl[r] = 1.0f / psum[r];
#pragma unroll
        for (int dt = 0; dt < 4; dt++)
#pragma unroll
            for (int r = 0; r < 4; r++) {
                int qq = qw + quad * 4 + r;
                int d = dt * 16 + lane16;
                att[(size_t)(b * TT + qq) * CC + h * DD + d] = f2b(O[dt][r] * rl[r]);
            }
    }
}

// ---------------------------------------------------------------------------
extern "C" void kernel_launch(void* const* d_in, const int* in_sizes, int n_in,
                              void* d_out, int out_size, void* d_ws, size_t ws_size,
                              hipStream_t stream) {
    const float* x     = (const float*)d_in[0];
    const float* Wqkv  = (const float*)d_in[1];
    const float* bqkv  = (const float*)d_in[2];
    const float* Wproj = (const float*)d_in[3];
    const float* bproj = (const float*)d_in[4];
    float* out = (float*)d_out;

    unsigned short* xb      = (unsigned short*)d_ws;            // [4096][1024]
    unsigned short* qkv_b   = xb      + (size_t)BT * CC;        // [4096][3072]
    unsigned short* Wqkv_t  = qkv_b   + (size_t)BT * C3;        // [3072][1024]
    unsigned short* Wproj_t = Wqkv_t  + (size_t)C3 * CC;        // [1024][1024]
    unsigned short* Vt      = Wproj_t + (size_t)CC * CC;        // [32][64][2048]
    unsigned short* att_b   = Vt      + (size_t)BB * HH * DD * TT; // [4096][1024]

    // 1) input cast + weight transposes (one launch)
    prep_kernel<<<3072, 256, 0, stream>>>(x, xb, Wqkv, Wproj, Wqkv_t, Wproj_t);

    // 2) QKV GEMM -> bf16 (Q pre-scaled by log2(e)/8; V also written transposed)
    {
        dim3 grid(C3 / 128, BT / 128);
        gemm_bt_kernel<unsigned short, true><<<grid, 256, 0, stream>>>(
            xb, Wqkv_t, bqkv, qkv_b, Vt, BT, C3, CC, 0.125f * 1.44269504f, CC);
    }
    // 3) flash attention (paired q-tiles, XCD-local heads, raw v_exp_f32)
    {
        dim3 grid(BB * HH, 16);
        attn_mfma_kernel<<<grid, 256, 0, stream>>>(qkv_b, Vt, att_b);
    }
    // 4) projection GEMM -> fp32 out
    {
        dim3 grid(CC / 128, BT / 128);
        gemm_bt_kernel<float, false><<<grid, 256, 0, stream>>>(
            att_b, Wproj_t, bproj, out, nullptr, BT, CC, CC, 1.0f, 0);
    }
}